// Round 1
// baseline (24760.818 us; speedup 1.0000x reference)
//
#include <hip/hip_runtime.h>

#define NB 4
#define NT 32
#define ND 768
#define NK 1024
#define NN 256
#define NINIT 4
#define NFRAMES 28
#define NM 1280     // NK + NN
#define NKT 16      // NK / 64

// ---------------- init: memory = first 4 frames, counts = 1 ----------------
__global__ __launch_bounds__(256) void k_init(const float* __restrict__ V,
                                              float* __restrict__ mem,
                                              float* __restrict__ cnt) {
    int gid = blockIdx.x * 256 + threadIdx.x;
    const int per_b = NK * ND / 4;                 // float4 per batch = 196608
    const float4* src = (const float4*)V;
    float4* dst = (float4*)mem;
    if (gid < NB * per_b) {
        int b = gid / per_b, r = gid % per_b;
        dst[(size_t)b * per_b + r] = src[(size_t)b * (NT * NN * ND / 4) + r];
    }
    if (gid < NB * NK) cnt[gid] = 1.0f;
}

// ---------------- cnorm[b,k] = ||c_k||^2 ----------------
__global__ __launch_bounds__(256) void k_cnorm(const float* __restrict__ C,
                                               float* __restrict__ cnorm) {
    int row  = blockIdx.x * 4 + (threadIdx.x >> 6);  // 0 .. NB*NK-1
    int lane = threadIdx.x & 63;
    const float* p = C + (size_t)row * ND;
    float s = 0.f;
#pragma unroll
    for (int j = 0; j < 12; ++j) { float v = p[lane + 64 * j]; s += v * v; }
#pragma unroll
    for (int off = 32; off; off >>= 1) s += __shfl_xor(s, off);
    if (lane == 0) cnorm[row] = s;
}

// ---------------- score tile + partial argmin ----------------
// grid = NB * 20 * 16 blocks; 64(m) x 64(k) tile, 4x4 register blocking.
__global__ __launch_bounds__(256) void k_score(
    const float* __restrict__ Cen,    // centers (B,K,D)
    const float* __restrict__ memFS,  // data rows 0..1023
    const float* __restrict__ V, int t,
    const float* __restrict__ cnorm,  // (B,K)
    float* __restrict__ pVal, int* __restrict__ pIdx)
{
    __shared__ float As[64][36];   // [m][d]  (pad 36: b128 reads 2-way max)
    __shared__ float Cs[32][68];   // [d][k]  (transposed; b128 over k, 2-way max)

    int bid = blockIdx.x;
    int kt = bid & 15;
    int mt = (bid >> 4) % 20;
    int b  = bid / (16 * 20);
    int tid = threadIdx.x;
    int tm = tid >> 4, tk = tid & 15;

    // A staging: 4 threads per row, 8 floats each
    int ar = tid >> 2;
    int ac = (tid & 3) * 8;
    int gm = mt * 64 + ar;
    const float* arow = (gm < NK)
        ? memFS + ((size_t)b * NK + gm) * ND
        : V + (((size_t)b * NT + t) * NN + (gm - NK)) * (size_t)ND;
    // C staging: lane-per-center-row, transposed store
    int ccol = tid & 63;
    int cdb  = tid >> 6;   // 0..3 -> d sub-block of 8
    const float* crow = Cen + ((size_t)b * NK + kt * 64 + ccol) * ND;

    float acc[4][4] = {{0.f}};

    for (int d0 = 0; d0 < ND; d0 += 32) {
        float4 a0 = *(const float4*)(arow + d0 + ac);
        float4 a1 = *(const float4*)(arow + d0 + ac + 4);
        float4 c0 = *(const float4*)(crow + d0 + cdb * 8);
        float4 c1 = *(const float4*)(crow + d0 + cdb * 8 + 4);
        __syncthreads();
        *(float4*)&As[ar][ac]     = a0;
        *(float4*)&As[ar][ac + 4] = a1;
        Cs[cdb * 8 + 0][ccol] = c0.x; Cs[cdb * 8 + 1][ccol] = c0.y;
        Cs[cdb * 8 + 2][ccol] = c0.z; Cs[cdb * 8 + 3][ccol] = c0.w;
        Cs[cdb * 8 + 4][ccol] = c1.x; Cs[cdb * 8 + 5][ccol] = c1.y;
        Cs[cdb * 8 + 6][ccol] = c1.z; Cs[cdb * 8 + 7][ccol] = c1.w;
        __syncthreads();
#pragma unroll
        for (int dd = 0; dd < 32; dd += 4) {
            float4 av[4], cv[4];
#pragma unroll
            for (int i = 0; i < 4; ++i) av[i] = *(const float4*)&As[tm * 4 + i][dd];
#pragma unroll
            for (int j = 0; j < 4; ++j) cv[j] = *(const float4*)&Cs[dd + j][tk * 4];
#pragma unroll
            for (int i = 0; i < 4; ++i) {
                float ax = av[i].x, ay = av[i].y, az = av[i].z, aw = av[i].w;
                acc[i][0] += ax * cv[0].x + ay * cv[1].x + az * cv[2].x + aw * cv[3].x;
                acc[i][1] += ax * cv[0].y + ay * cv[1].y + az * cv[2].y + aw * cv[3].y;
                acc[i][2] += ax * cv[0].z + ay * cv[1].z + az * cv[2].z + aw * cv[3].z;
                acc[i][3] += ax * cv[0].w + ay * cv[1].w + az * cv[2].w + aw * cv[3].w;
            }
        }
    }

    // score = cnorm[k] - 2*dot ; per-row argmin over this k-tile
    float cn[4];
#pragma unroll
    for (int j = 0; j < 4; ++j) cn[j] = cnorm[b * NK + kt * 64 + tk * 4 + j];

    float bv[4]; int bi[4];
#pragma unroll
    for (int i = 0; i < 4; ++i) {
        bv[i] = 1e30f; bi[i] = 0x7fffffff;
#pragma unroll
        for (int j = 0; j < 4; ++j) {
            float s = cn[j] - 2.0f * acc[i][j];
            int kg = kt * 64 + tk * 4 + j;
            if (s < bv[i]) { bv[i] = s; bi[i] = kg; }
        }
    }
#pragma unroll
    for (int off = 1; off < 16; off <<= 1) {
#pragma unroll
        for (int i = 0; i < 4; ++i) {
            float ov = __shfl_xor(bv[i], off);
            int   oi = __shfl_xor(bi[i], off);
            if (ov < bv[i] || (ov == bv[i] && oi < bi[i])) { bv[i] = ov; bi[i] = oi; }
        }
    }
    if (tk == 0) {
#pragma unroll
        for (int i = 0; i < 4; ++i) {
            int m = mt * 64 + tm * 4 + i;
            pVal[((size_t)b * NM + m) * NKT + kt] = bv[i];
            pIdx[((size_t)b * NM + m) * NKT + kt] = bi[i];
        }
    }
}

// ---------------- merge partial argmins ----------------
__global__ __launch_bounds__(256) void k_merge(const float* __restrict__ pVal,
                                               const int* __restrict__ pIdx,
                                               int* __restrict__ assign) {
    int gid = blockIdx.x * 256 + threadIdx.x;
    if (gid >= NB * NM) return;
    float bv = 1e30f; int bi = 0x7fffffff;
#pragma unroll
    for (int kt = 0; kt < NKT; ++kt) {
        float v = pVal[(size_t)gid * NKT + kt];
        int   i = pIdx[(size_t)gid * NKT + kt];
        if (v < bv) { bv = v; bi = i; }   // idx ascending with kt -> first-min kept
    }
    assign[gid] = bi;
}

// ---------------- center update (one wave per (b,k)) ----------------
__global__ __launch_bounds__(256) void k_update(
    const float* __restrict__ Cen,    // centers_in (kept for empty clusters)
    const float* __restrict__ memFS,  // data rows 0..1023
    const float* __restrict__ V, int t,
    const float* __restrict__ cntFS,  // weights for memory rows
    const int* __restrict__ assign,
    float* __restrict__ Cout, float* __restrict__ cntOut)
{
    int row  = blockIdx.x * 4 + (threadIdx.x >> 6);  // b*NK + k
    int lane = threadIdx.x & 63;
    int b = row >> 10, k = row & 1023;
    float acc[12] = {0.f};
    float sumw = 0.f;
    const int* as = assign + (size_t)b * NM;
    for (int ch = 0; ch < 20; ++ch) {
        int a = as[ch * 64 + lane];
        unsigned long long mask = __ballot(a == k);
        while (mask) {
            int bit = __ffsll((long long)mask) - 1;
            mask &= mask - 1;
            int mm = ch * 64 + bit;
            float w = (mm < NK) ? cntFS[b * NK + mm] : 1.0f;
            const float* drow = (mm < NK)
                ? memFS + ((size_t)b * NK + mm) * ND
                : V + (((size_t)b * NT + t) * NN + (mm - NK)) * (size_t)ND;
            sumw += w;
#pragma unroll
            for (int j = 0; j < 12; ++j) acc[j] += w * drow[lane + 64 * j];
        }
    }
    float inv = 1.0f / (sumw + 1e-8f);
    bool empty = sumw < 1e-6f;
    const float* crow = Cen + (size_t)row * ND;
#pragma unroll
    for (int j = 0; j < 12; ++j) {
        float v = empty ? crow[lane + 64 * j] : acc[j] * inv;
        Cout[(size_t)row * ND + lane + 64 * j] = v;
    }
    if (lane == 0) cntOut[row] = sumw;
}

// ---------------- host ----------------
extern "C" void kernel_launch(void* const* d_in, const int* in_sizes, int n_in,
                              void* d_out, int out_size, void* d_ws, size_t ws_size,
                              hipStream_t stream) {
    const float* V = (const float*)d_in[0];
    float* out = (float*)d_out;
    char* ws = (char*)d_ws;

    const size_t memFloats = (size_t)NB * NK * ND;     // 3,145,728
    float* mem0 = (float*)ws;
    float* mem1 = mem0 + memFloats;
    float* cnt0 = mem1 + memFloats;
    float* cnt1 = cnt0 + NB * NK;
    float* cntS = cnt1 + NB * NK;                      // scratch counts (iter1)
    float* cnor = cntS + NB * NK;
    float* pVal = cnor + NB * NK;
    int*   pIdx = (int*)(pVal + (size_t)NB * NM * NKT);
    int*   assign = (int*)(pIdx + (size_t)NB * NM * NKT);

    k_init<<<3072, 256, 0, stream>>>(V, mem0, cnt0);

    float* mem[2] = {mem0, mem1};
    float* cnt[2] = {cnt0, cnt1};

    for (int f = 0; f < NFRAMES; ++f) {
        int s = f & 1;
        int t = NINIT + f;
        float* mFS = mem[s];
        float* cFS = cnt[s];

        // ---- k-means iteration 1: centers = mFS -> d_out ----
        k_cnorm<<<1024, 256, 0, stream>>>(mFS, cnor);
        k_score<<<1280, 256, 0, stream>>>(mFS, mFS, V, t, cnor, pVal, pIdx);
        k_merge<<<20, 256, 0, stream>>>(pVal, pIdx, assign);
        k_update<<<1024, 256, 0, stream>>>(mFS, mFS, V, t, cFS, assign, out, cntS);

        // ---- k-means iteration 2: centers = d_out -> mem[1-s] (or d_out at end) ----
        k_cnorm<<<1024, 256, 0, stream>>>(out, cnor);
        k_score<<<1280, 256, 0, stream>>>(out, mFS, V, t, cnor, pVal, pIdx);
        k_merge<<<20, 256, 0, stream>>>(pVal, pIdx, assign);
        float* dst = (f == NFRAMES - 1) ? out : mem[1 - s];
        k_update<<<1024, 256, 0, stream>>>(out, mFS, V, t, cFS, assign, dst, cnt[1 - s]);
    }
}

// Round 3
// 7404.390 us; speedup vs baseline: 3.3441x; 3.3441x over previous
//
#include <hip/hip_runtime.h>

#define NB 4
#define NT 32
#define ND 768
#define NK 1024
#define NN 256
#define NINIT 4
#define NFRAMES 28
#define NM 1280

typedef _Float16 f16;
typedef f16 f16x8 __attribute__((ext_vector_type(8)));
typedef float f32x4 __attribute__((ext_vector_type(4)));

#define GLOAD_LDS(g, s) __builtin_amdgcn_global_load_lds( \
    (const __attribute__((address_space(1))) void*)(g),   \
    (__attribute__((address_space(3))) void*)(s), 16, 0, 0)

// row-dependent XOR swizzle, closed within a 64-byte row (bits 4-5 only).
// group = 4*(r&1) + (d4 ^ ((r>>1)&3)) -> 2 lanes per bank group on b128 reads.
__device__ __forceinline__ int swz(int r) { return ((r >> 1) & 3) << 4; }

// ---------------- init: mem copy, counts=1, f16 split, cnorm, packed reset ----
__global__ __launch_bounds__(256) void k_init(
    const float* __restrict__ V, float* __restrict__ mem, float* __restrict__ cnt,
    f16* __restrict__ dH, f16* __restrict__ dL,
    float* __restrict__ cnorm, unsigned long long* __restrict__ packed0)
{
    int row = blockIdx.x * 4 + (threadIdx.x >> 6);   // 0..4095
    int lane = threadIdx.x & 63;
    int b = row >> 10, k = row & 1023;
    const float* src = V + ((size_t)b * NT * NN + k) * ND;
    float* mrow = mem + (size_t)row * ND;
    f16* hrow = dH + ((size_t)b * NM + k) * ND;
    f16* lrow = dL + ((size_t)b * NM + k) * ND;
    float s2 = 0.f;
#pragma unroll
    for (int j = 0; j < 12; ++j) {
        float x = src[lane + 64 * j];
        mrow[lane + 64 * j] = x;
        f16 h = (f16)x;
        hrow[lane + 64 * j] = h;
        lrow[lane + 64 * j] = (f16)(x - (float)h);
        s2 += x * x;
    }
#pragma unroll
    for (int off = 32; off; off >>= 1) s2 += __shfl_xor(s2, off);
    if (lane == 0) { cnorm[row] = s2; cnt[row] = 1.0f; packed0[(size_t)b * NM + k] = ~0ull; }
    if (lane == 1 && k < NN) packed0[(size_t)b * NM + NK + k] = ~0ull;
}

// ---------------- per-frame: split the 256 new tokens ----------------
__global__ __launch_bounds__(256) void k_prep(const float* __restrict__ V, int t,
                                              f16* __restrict__ dH, f16* __restrict__ dL) {
    int row = blockIdx.x * 4 + (threadIdx.x >> 6);  // 0..1023
    int lane = threadIdx.x & 63;
    int b = row >> 8, n = row & 255;
    const float* src = V + (((size_t)b * NT + t) * NN + n) * ND;
    f16* hrow = dH + ((size_t)b * NM + NK + n) * ND;
    f16* lrow = dL + ((size_t)b * NM + NK + n) * ND;
#pragma unroll
    for (int j = 0; j < 12; ++j) {
        float x = src[lane + 64 * j];
        f16 h = (f16)x;
        hrow[lane + 64 * j] = h;
        lrow[lane + 64 * j] = (f16)(x - (float)h);
    }
}

// ---------------- MFMA score + argmin (packed atomicMin) ----------------
// grid = 640 blocks x 128 threads. Block tile 128(M) x 64(Ncenters), 2 waves
// stacked on M, each wave 64x64 via 4x4 grid of 16x16x32 f16 MFMAs.
// dot(x,c) = Ah*Bh + Ah*Bl + Al*Bh  (split-f16, fp32 accumulate)
__global__ __launch_bounds__(128) void k_score(
    const f16* __restrict__ AH, const f16* __restrict__ AL,   // (B, NM, ND)
    const f16* __restrict__ BH, const f16* __restrict__ BL,   // (B, bRows, ND)
    int bRows,
    const float* __restrict__ cnorm,                          // (B, NK)
    unsigned long long* __restrict__ packed)                  // (B, NM)
{
    __shared__ float4 ldsbuf[1536];   // 24 KB: AH 8K | AL 8K | BH 4K | BL 4K
    char* lds = (char*)ldsbuf;
    int bid = blockIdx.x;
    int sz = (bid & 7) * 80 + (bid >> 3);      // XCD-aware (640 % 8 == 0)
    int b = sz / 160;
    int rem = sz - b * 160;
    int mt = rem >> 4, kt = rem & 15;
    int tid = threadIdx.x;
    int w = tid >> 6, l = tid & 63;

    // staging source pointers (pre-swizzled global addr -> linear LDS dest)
    const char* sp[12];
#pragma unroll
    for (int i = 0; i < 12; ++i) {
        int j = w * 12 + i;
        const f16* base; int r, grow;
        if (j < 8)       { r = 16 * j + (l >> 2);        grow = b * NM + mt * 128 + r;    base = AH; }
        else if (j < 16) { r = 16 * (j - 8) + (l >> 2);  grow = b * NM + mt * 128 + r;    base = AL; }
        else if (j < 20) { r = 16 * (j - 16) + (l >> 2); grow = b * bRows + kt * 64 + r;  base = BH; }
        else             { r = 16 * (j - 20) + (l >> 2); grow = b * bRows + kt * 64 + r;  base = BL; }
        int colB = ((l & 3) * 16) ^ swz(r);              // inverse of read-side swizzle
        sp[i] = (const char*)(base + (size_t)grow * ND) + colB;
    }

    // fragment read offsets (swizzled)
    int aoff[4], boff[4];
#pragma unroll
    for (int mi = 0; mi < 4; ++mi) {
        int r = w * 64 + mi * 16 + (l & 15);
        aoff[mi] = r * 64 + (((l >> 4) * 16) ^ swz(r));
    }
#pragma unroll
    for (int nj = 0; nj < 4; ++nj) {
        int r = nj * 16 + (l & 15);
        boff[nj] = r * 64 + (((l >> 4) * 16) ^ swz(r));
    }

    f32x4 acc[4][4] = {};

    for (int c = 0; c < 24; ++c) {                 // 24 chunks of K=32 halves
#pragma unroll
        for (int i = 0; i < 12; ++i) {
            GLOAD_LDS(sp[i], lds + (w * 12 + i) * 1024);
            sp[i] += 64;
        }
        __syncthreads();                           // drains vmcnt before barrier
        f16x8 ah[4], al[4], bh[4], bl[4];
#pragma unroll
        for (int mi = 0; mi < 4; ++mi) {
            ah[mi] = *(const f16x8*)(lds + aoff[mi]);
            al[mi] = *(const f16x8*)(lds + 8192 + aoff[mi]);
        }
#pragma unroll
        for (int nj = 0; nj < 4; ++nj) {
            bh[nj] = *(const f16x8*)(lds + 16384 + boff[nj]);
            bl[nj] = *(const f16x8*)(lds + 20480 + boff[nj]);
        }
#pragma unroll
        for (int mi = 0; mi < 4; ++mi)
#pragma unroll
            for (int nj = 0; nj < 4; ++nj) {
                acc[mi][nj] = __builtin_amdgcn_mfma_f32_16x16x32_f16(ah[mi], bh[nj], acc[mi][nj], 0, 0, 0);
                acc[mi][nj] = __builtin_amdgcn_mfma_f32_16x16x32_f16(ah[mi], bl[nj], acc[mi][nj], 0, 0, 0);
                acc[mi][nj] = __builtin_amdgcn_mfma_f32_16x16x32_f16(al[mi], bh[nj], acc[mi][nj], 0, 0, 0);
            }
        __syncthreads();
    }

    // epilogue: score = cnorm[k] - 2*dot; per-row argmin -> packed atomicMin
    int colb = kt * 64 + (l & 15);
    float cn[4];
#pragma unroll
    for (int nj = 0; nj < 4; ++nj) cn[nj] = cnorm[b * NK + colb + nj * 16];
    size_t prow = (size_t)b * NM + mt * 128 + w * 64 + (l >> 4) * 4;
#pragma unroll
    for (int mi = 0; mi < 4; ++mi) {
#pragma unroll
        for (int rg = 0; rg < 4; ++rg) {
            float bv = 1e30f; int bi = 0;
#pragma unroll
            for (int nj = 0; nj < 4; ++nj) {
                float s = cn[nj] - 2.0f * acc[mi][nj][rg];
                int ki = colb + nj * 16;
                if (s < bv) { bv = s; bi = ki; }
            }
#pragma unroll
            for (int off = 1; off < 16; off <<= 1) {
                float ov = __shfl_xor(bv, off);
                int   oi = __shfl_xor(bi, off);
                if (ov < bv || (ov == bv && oi < bi)) { bv = ov; bi = oi; }
            }
            if ((l & 15) == 0) {
                unsigned u = __float_as_uint(bv);
                unsigned key = (u >> 31) ? ~u : (u | 0x80000000u);
                atomicMin(&packed[prow + mi * 16 + rg],
                          ((unsigned long long)key << 32) | (unsigned)bi);
            }
        }
    }
}

// ---------------- center update + fused split/cnorm/packed-reset ----------
__global__ __launch_bounds__(256) void k_update(
    const float* __restrict__ Cen, const float* __restrict__ memFS,
    const float* __restrict__ V, int t,
    const float* __restrict__ cntFS,
    const unsigned long long* __restrict__ packedIn,
    float* __restrict__ Cout, float* __restrict__ cntOut,
    f16* __restrict__ outH, f16* __restrict__ outL, int outStride,
    float* __restrict__ cnormOut, unsigned long long* __restrict__ packedReset)
{
    int row = blockIdx.x * 4 + (threadIdx.x >> 6);   // b*NK + k
    int lane = threadIdx.x & 63;
    int b = row >> 10, k = row & 1023;
    const unsigned long long* ps = packedIn + (size_t)b * NM;
    float acc[12] = {};
    float sumw = 0.f;
    for (int ch = 0; ch < 20; ++ch) {
        int a = (int)(unsigned)(ps[ch * 64 + lane] & 0xffffffffull);
        unsigned long long mask = __ballot(a == k);
        while (mask) {
            int bit = __ffsll((long long)mask) - 1;
            mask &= mask - 1;
            int mm = ch * 64 + bit;
            float wgt = (mm < NK) ? cntFS[b * NK + mm] : 1.0f;
            const float* drow = (mm < NK)
                ? memFS + ((size_t)b * NK + mm) * ND
                : V + (((size_t)b * NT + t) * NN + (mm - NK)) * (size_t)ND;
            sumw += wgt;
#pragma unroll
            for (int j = 0; j < 12; ++j) acc[j] += wgt * drow[lane + 64 * j];
        }
    }
    float inv = 1.0f / (sumw + 1e-8f);
    bool empty = sumw < 1e-6f;
    const float* crow = Cen + (size_t)row * ND;
    float* orow = Cout + (size_t)row * ND;
    f16* hrow = outH + ((size_t)b * outStride + k) * ND;
    f16* lrow = outL + ((size_t)b * outStride + k) * ND;
    float s2 = 0.f;
#pragma unroll
    for (int j = 0; j < 12; ++j) {
        float v = empty ? crow[lane + 64 * j] : acc[j] * inv;
        orow[lane + 64 * j] = v;
        f16 h = (f16)v;
        hrow[lane + 64 * j] = h;
        lrow[lane + 64 * j] = (f16)(v - (float)h);
        s2 += v * v;
    }
#pragma unroll
    for (int off = 32; off; off >>= 1) s2 += __shfl_xor(s2, off);
    if (lane == 0) { cnormOut[row] = s2; cntOut[row] = sumw; packedReset[(size_t)b * NM + k] = ~0ull; }
    if (lane == 1 && k < NN) packedReset[(size_t)b * NM + NK + k] = ~0ull;
}

// ---------------- host ----------------
extern "C" void kernel_launch(void* const* d_in, const int* in_sizes, int n_in,
                              void* d_out, int out_size, void* d_ws, size_t ws_size,
                              hipStream_t stream) {
    const float* V = (const float*)d_in[0];
    float* out = (float*)d_out;
    char* p = (char*)d_ws;
    auto take = [&](size_t bytes) { char* r = p; p += (bytes + 255) & ~(size_t)255; return r; };
    const size_t memB = (size_t)NB * NK * ND * 4;
    float* mem0 = (float*)take(memB);
    float* mem1 = (float*)take(memB);
    float* cnt0 = (float*)take(NB * NK * 4);
    float* cnt1 = (float*)take(NB * NK * 4);
    float* cntS = (float*)take(NB * NK * 4);
    float* cnor = (float*)take(NB * NK * 4);
    unsigned long long* packed0 = (unsigned long long*)take(NB * NM * 8);
    unsigned long long* packed1 = (unsigned long long*)take(NB * NM * 8);
    f16* dataH = (f16*)take((size_t)NB * NM * ND * 2);
    f16* dataL = (f16*)take((size_t)NB * NM * ND * 2);
    f16* cenH  = (f16*)take((size_t)NB * NK * ND * 2);
    f16* cenL  = (f16*)take((size_t)NB * NK * ND * 2);

    k_init<<<1024, 256, 0, stream>>>(V, mem0, cnt0, dataH, dataL, cnor, packed0);

    float* mem[2] = {mem0, mem1};
    float* cnt[2] = {cnt0, cnt1};

    for (int f = 0; f < NFRAMES; ++f) {
        int s = f & 1, t = NINIT + f;
        float* mFS = mem[s];
        float* cFS = cnt[s];

        k_prep<<<256, 256, 0, stream>>>(V, t, dataH, dataL);

        // iter 1: centers = memory rows (their split lives in dataH/L rows 0..1023)
        k_score<<<640, 128, 0, stream>>>(dataH, dataL, dataH, dataL, NM, cnor, packed0);
        k_update<<<1024, 256, 0, stream>>>(mFS, mFS, V, t, cFS, packed0, out, cntS,
                                           cenH, cenL, NK, cnor, packed1);

        // iter 2: centers = tmp centers in d_out (split in cenH/L)
        k_score<<<640, 128, 0, stream>>>(dataH, dataL, cenH, cenL, NK, cnor, packed1);
        float* dst = (f == NFRAMES - 1) ? out : mem[1 - s];
        k_update<<<1024, 256, 0, stream>>>(out, mFS, V, t, cFS, packed1, dst, cnt[1 - s],
                                           dataH, dataL, NM, cnor, packed0);
    }
}